// Round 4
// baseline (10793.443 us; speedup 1.0000x reference)
//
#include <hip/hip_runtime.h>

#define NPTS 2048
#define KNN_K 20
#define BATCH 16

constexpr float EPSV   = 1e-5f;
constexpr float SLOPEV = 0.2f;

__device__ __forceinline__ float dot4(float4 a, float4 b, float acc) {
  acc = fmaf(a.x, b.x, acc);
  acc = fmaf(a.y, b.y, acc);
  acc = fmaf(a.z, b.z, acc);
  acc = fmaf(a.w, b.w, acc);
  return acc;
}

// ---------------- squared norms: one thread per (b,n) ----------------
template<int C>
__global__ void sq_kernel(const float* __restrict__ XT, float* __restrict__ SQ) {
  int i = blockIdx.x * 256 + threadIdx.x;          // i = b*NPTS + n
  const float* r = XT + (long)i * C;
  float s = 0.f;
  if constexpr (C % 4 == 0) {
    const float4* r4 = (const float4*)r;
    #pragma unroll
    for (int c = 0; c < C / 4; ++c) { float4 v = r4[c]; s = dot4(v, v, s); }
  } else {
    #pragma unroll
    for (int c = 0; c < C; ++c) s = fmaf(r[c], r[c], s);
  }
  SQ[i] = s;
}

// ---------------- KNN: 2 threads per row (halves of m-range) ----------------
// pd = 2*dot(xn,xm) - sq[n] - sq[m]; top-20 by value desc, ties -> lower index
template<int C>
__global__ __launch_bounds__(256, 1) void knn_kernel(const float* __restrict__ XT,
                                                     const float* __restrict__ SQ,
                                                     int* __restrict__ IDX) {
  __shared__ float ld[256][KNN_K];
  __shared__ int   li[256][KNN_K];
  int t    = threadIdx.x;
  int gr   = blockIdx.x * 128 + (t >> 1);          // global row = b*NPTS+n
  int b    = gr >> 11;
  int half = t & 1;

  float sqn = SQ[gr];
  const float* xb  = XT + ((long)b << 11) * C;
  const float* sqb = SQ + ((long)b << 11);

  float topd[KNN_K]; int topi[KNN_K];
  #pragma unroll
  for (int j = 0; j < KNN_K; ++j) { topd[j] = -3e38f; topi[j] = 0; }

  if constexpr (C % 4 == 0) {
    float4 xn4[C / 4];
    const float4* xr = (const float4*)(XT + (long)gr * C);
    #pragma unroll
    for (int c = 0; c < C / 4; ++c) xn4[c] = xr[c];

    int m0 = half << 10;
    for (int mm = 0; mm < 1024; ++mm) {
      int m = m0 + mm;
      const float4* xm4 = (const float4*)(xb + (long)m * C);
      float dot = 0.f;
      #pragma unroll
      for (int c = 0; c < C / 4; ++c) dot = dot4(xn4[c], xm4[c], dot);
      float pd = fmaf(2.f, dot, -sqn) - sqb[m];
      if (pd > topd[KNN_K - 1]) {
        float d = pd; int ii = m;
        #pragma unroll
        for (int j = 0; j < KNN_K; ++j) {
          bool sw = d > topd[j];
          float td = sw ? d : topd[j]; float dd = sw ? topd[j] : d;
          int   ti = sw ? ii : topi[j]; int  di = sw ? topi[j] : ii;
          topd[j] = td; d = dd; topi[j] = ti; ii = di;
        }
      }
    }
  } else {
    float xn[C];
    const float* xr = XT + (long)gr * C;
    #pragma unroll
    for (int c = 0; c < C; ++c) xn[c] = xr[c];

    int m0 = half << 10;
    for (int mm = 0; mm < 1024; ++mm) {
      int m = m0 + mm;
      const float* xm = xb + (long)m * C;
      float dot = 0.f;
      #pragma unroll
      for (int c = 0; c < C; ++c) dot = fmaf(xn[c], xm[c], dot);
      float pd = fmaf(2.f, dot, -sqn) - sqb[m];
      if (pd > topd[KNN_K - 1]) {
        float d = pd; int ii = m;
        #pragma unroll
        for (int j = 0; j < KNN_K; ++j) {
          bool sw = d > topd[j];
          float td = sw ? d : topd[j]; float dd = sw ? topd[j] : d;
          int   ti = sw ? ii : topi[j]; int  di = sw ? topi[j] : ii;
          topd[j] = td; d = dd; topi[j] = ti; ii = di;
        }
      }
    }
  }

  #pragma unroll
  for (int j = 0; j < KNN_K; ++j) { ld[t][j] = topd[j]; li[t][j] = topi[j]; }
  __syncthreads();

  if (t < 128) {
    int a = 2 * t, c2 = 2 * t + 1;
    int grow = blockIdx.x * 128 + t;
    int* dst = IDX + (long)grow * KNN_K;
    int ia = 0, ib = 0;
    for (int j = 0; j < KNN_K; ++j) {
      float da = ld[a][ia], db = ld[c2][ib];
      bool ta = (da >= db);                        // tie -> low half (lower m) first
      dst[j] = ta ? li[a][ia] : li[c2][ib];
      ia += ta ? 1 : 0; ib += ta ? 0 : 1;
    }
  }
}

// ---------------- edge conv stage 1 (C=3, scalar path) ----------------
template<int O, int C>
__global__ __launch_bounds__(256, 2) void conv_small(const float* __restrict__ XTin,
                                                     const int* __restrict__ IDX,
                                                     const float* __restrict__ W,
                                                     const float* __restrict__ gg,
                                                     const float* __restrict__ bbias,
                                                     const float* __restrict__ mmean,
                                                     const float* __restrict__ vvar,
                                                     float* __restrict__ XTout) {
  constexpr int G   = 256 / O;        // threads per o
  constexpr int KPG = KNN_K / G;      // k's per thread
  __shared__ float cols[KNN_K + 1][C];

  int bid = blockIdx.x;               // = b*NPTS + n
  int b = bid >> 11, n = bid & 2047;
  int t = threadIdx.x;
  long rowbase = ((long)b << 11);
  const int* idxp = IDX + (long)bid * KNN_K;

  for (int e = t; e < (KNN_K + 1) * C; e += 256) {
    int col = e / C, c = e - col * C;
    int j = (col == 0) ? n : idxp[col - 1];
    cols[col][c] = XTin[(rowbase + j) * C + c];
  }
  __syncthreads();

  int o = t / G, kg = t - o * G;
  const float* wrow = W + o * (2 * C);

  float acc[KPG];
  #pragma unroll
  for (int q = 0; q < KPG; ++q) acc[q] = 0.f;
  float s1 = 0.f, u2 = 0.f;

  #pragma unroll
  for (int c = 0; c < C; ++c) {
    float w1 = wrow[c];
    float w2 = wrow[C + c];
    float xn = cols[0][c];
    s1 = fmaf(w1, xn, s1);
    u2 = fmaf(w2, xn, u2);
    #pragma unroll
    for (int q = 0; q < KPG; ++q) {
      int k = kg * KPG + q;
      acc[q] = fmaf(w1, cols[1 + k][c], acc[q]);
    }
  }

  float sc = gg[o] / sqrtf(vvar[o] + EPSV);
  float sh = bbias[o] - mmean[o] * sc;
  float vmax = -3e38f;
  #pragma unroll
  for (int q = 0; q < KPG; ++q) {
    float z = acc[q] - s1 + u2;
    float y = fmaf(sc, z, sh);
    y = (y >= 0.f) ? y : SLOPEV * y;
    vmax = fmaxf(vmax, y);
  }
  #pragma unroll
  for (int off = 1; off < G; off <<= 1)
    vmax = fmaxf(vmax, __shfl_xor(vmax, off, 64));
  if (kg == 0) XTout[(rowbase + n) * O + o] = vmax;
}

// ---------------- edge conv stages 2-4 (vector path, 64 o-groups x 4 k-groups) --
// thread t: to = t>>2 owns O/64 channels {to, to+64, ...}; tk = t&3 owns k in
// [tk*5, tk*5+5). One neighbor ds_read_b128 feeds (O/64)*4 FMAs. LDS rows
// padded to C+4 floats so the 4 k-group columns hit disjoint bank groups.
template<int O, int C>
__global__ __launch_bounds__(256, 2) void conv_fast(const float* __restrict__ XTin,
                                                    const int* __restrict__ IDX,
                                                    const float* __restrict__ W,
                                                    const float* __restrict__ gg,
                                                    const float* __restrict__ bbias,
                                                    const float* __restrict__ mmean,
                                                    const float* __restrict__ vvar,
                                                    float* __restrict__ XTout) {
  static_assert(C % 4 == 0 && O % 64 == 0, "conv_fast shape");
  constexpr int NO = O / 64;          // o's per thread
  constexpr int CP = C + 4;           // padded LDS row stride (floats)
  constexpr int C4 = C / 4;
  __shared__ float cols[KNN_K + 1][CP];

  int bid = blockIdx.x;               // = b*NPTS + n
  int b = bid >> 11, n = bid & 2047;
  int t = threadIdx.x;
  long rowbase = ((long)b << 11);
  const int* idxp = IDX + (long)bid * KNN_K;

  for (int e = t; e < (KNN_K + 1) * C4; e += 256) {
    int col = e / C4, c4 = e - col * C4;
    int j = (col == 0) ? n : idxp[col - 1];
    *(float4*)&cols[col][c4 * 4] = *(const float4*)(XTin + (rowbase + j) * C + c4 * 4);
  }
  __syncthreads();

  int to = t >> 2, tk = t & 3;

  float acc[NO][5];
  float s1[NO], u2[NO];
  #pragma unroll
  for (int i = 0; i < NO; ++i) {
    s1[i] = 0.f; u2[i] = 0.f;
    #pragma unroll
    for (int q = 0; q < 5; ++q) acc[i][q] = 0.f;
  }

  for (int c4 = 0; c4 < C4; ++c4) {
    float4 xn = *(const float4*)&cols[0][c4 * 4];
    float4 nb[5];
    #pragma unroll
    for (int q = 0; q < 5; ++q)
      nb[q] = *(const float4*)&cols[1 + tk * 5 + q][c4 * 4];
    #pragma unroll
    for (int i = 0; i < NO; ++i) {
      const float* wrow = W + (to + i * 64) * (2 * C);
      float4 w1 = *(const float4*)(wrow + c4 * 4);
      float4 w2 = *(const float4*)(wrow + C + c4 * 4);
      s1[i] = dot4(w1, xn, s1[i]);
      u2[i] = dot4(w2, xn, u2[i]);
      #pragma unroll
      for (int q = 0; q < 5; ++q) acc[i][q] = dot4(w1, nb[q], acc[i][q]);
    }
  }

  #pragma unroll
  for (int i = 0; i < NO; ++i) {
    int o = to + i * 64;
    float sc = gg[o] / sqrtf(vvar[o] + EPSV);
    float sh = bbias[o] - mmean[o] * sc;
    float vmax = -3e38f;
    #pragma unroll
    for (int q = 0; q < 5; ++q) {
      float z = acc[i][q] - s1[i] + u2[i];
      float y = fmaf(sc, z, sh);
      y = (y >= 0.f) ? y : SLOPEV * y;
      vmax = fmaxf(vmax, y);
    }
    vmax = fmaxf(vmax, __shfl_xor(vmax, 1, 64));
    vmax = fmaxf(vmax, __shfl_xor(vmax, 2, 64));
    if (tk == 0) XTout[(rowbase + n) * O + o] = vmax;
  }
}

// ---------------- final: y[b,o] = max_n act(s*W5·cat[b,:,n] + t) ----------------
__global__ __launch_bounds__(256, 2) void final_kernel(const float* __restrict__ X1,
                                                       const float* __restrict__ X2,
                                                       const float* __restrict__ X3,
                                                       const float* __restrict__ X4,
                                                       const float* __restrict__ W5,
                                                       const float* __restrict__ g5,
                                                       const float* __restrict__ b5,
                                                       const float* __restrict__ m5,
                                                       const float* __restrict__ v5,
                                                       float* __restrict__ RED) {
  __shared__ float tile[16][512];
  int bid = blockIdx.x;                 // b*128 + chunk
  int b = bid >> 7, chunk = bid & 127;
  int n0 = chunk * 16;
  int t = threadIdx.x;

  for (int e = t; e < 16 * 128; e += 256) {
    int nn = e >> 7, c4 = e & 127;
    int c = c4 * 4;
    long row = ((long)b << 11) + n0 + nn;
    float4 v;
    if      (c < 64)  v = *(const float4*)(X1 + row * 64  + c);
    else if (c < 128) v = *(const float4*)(X2 + row * 64  + (c - 64));
    else if (c < 256) v = *(const float4*)(X3 + row * 128 + (c - 128));
    else              v = *(const float4*)(X4 + row * 256 + (c - 256));
    *(float4*)&tile[nn][c] = v;
  }
  __syncthreads();

  int o = t;
  const float* wrow = W5 + o * 512;
  float acc[16];
  #pragma unroll
  for (int q = 0; q < 16; ++q) acc[q] = 0.f;
  for (int c4 = 0; c4 < 128; ++c4) {
    float4 w = *(const float4*)(wrow + c4 * 4);
    #pragma unroll
    for (int q = 0; q < 16; ++q) {
      float4 xv = *(const float4*)&tile[q][c4 * 4];
      acc[q] = dot4(w, xv, acc[q]);
    }
  }
  float sc = g5[o] / sqrtf(v5[o] + EPSV);
  float sh = b5[o] - m5[o] * sc;
  float vmax = -3e38f;
  #pragma unroll
  for (int q = 0; q < 16; ++q) {
    float y = fmaf(sc, acc[q], sh);
    y = (y >= 0.f) ? y : SLOPEV * y;
    vmax = fmaxf(vmax, y);
  }
  RED[((long)b * 256 + o) * 128 + chunk] = vmax;
}

__global__ void reduce_kernel(const float* __restrict__ RED, float* __restrict__ out) {
  int i = blockIdx.x * 256 + threadIdx.x;   // 4096 outputs
  const float* r = RED + (long)i * 128;
  float v = r[0];
  for (int j = 1; j < 128; ++j) v = fmaxf(v, r[j]);
  out[i] = v;
}

extern "C" void kernel_launch(void* const* d_in, const int* in_sizes, int n_in,
                              void* d_out, int out_size, void* d_ws, size_t ws_size,
                              hipStream_t stream) {
  (void)in_sizes; (void)n_in; (void)out_size; (void)ws_size;
  const float* pc = (const float*)d_in[0];                 // (16,2048,3) row-major = XT0
  const float* W1 = (const float*)d_in[1];
  const float* g1 = (const float*)d_in[2];
  const float* b1 = (const float*)d_in[3];
  const float* m1 = (const float*)d_in[4];
  const float* v1 = (const float*)d_in[5];
  const float* W2 = (const float*)d_in[6];
  const float* g2 = (const float*)d_in[7];
  const float* b2 = (const float*)d_in[8];
  const float* m2 = (const float*)d_in[9];
  const float* v2 = (const float*)d_in[10];
  const float* W3 = (const float*)d_in[11];
  const float* g3 = (const float*)d_in[12];
  const float* b3 = (const float*)d_in[13];
  const float* m3 = (const float*)d_in[14];
  const float* v3 = (const float*)d_in[15];
  const float* W4 = (const float*)d_in[16];
  const float* g4 = (const float*)d_in[17];
  const float* b4 = (const float*)d_in[18];
  const float* m4 = (const float*)d_in[19];
  const float* v4 = (const float*)d_in[20];
  const float* W5 = (const float*)d_in[21];
  const float* g5 = (const float*)d_in[22];
  const float* b5 = (const float*)d_in[23];
  const float* m5 = (const float*)d_in[24];
  const float* v5 = (const float*)d_in[25];
  float* out = (float*)d_out;

  // workspace carving (floats), all row-major [b][n][C]
  float* XT1 = (float*)d_ws;            // 16*2048*64
  float* XT2 = XT1 + 2097152;           // 16*2048*64
  float* XT3 = XT2 + 2097152;           // 16*2048*128
  float* XT4 = XT3 + 4194304;           // 16*2048*256
  float* SQ  = XT4 + 8388608;           // 16*2048
  float* RED = SQ  + 32768;             // 16*256*128
  int*   IDX = (int*)(RED + 524288);    // 16*2048*20

  const int BN = BATCH * NPTS;          // 32768

  // stage 1 (C=3 from pc)
  sq_kernel<3><<<BN / 256, 256, 0, stream>>>(pc, SQ);
  knn_kernel<3><<<BN / 128, 256, 0, stream>>>(pc, SQ, IDX);
  conv_small<64, 3><<<BN, 256, 0, stream>>>(pc, IDX, W1, g1, b1, m1, v1, XT1);
  // stage 2
  sq_kernel<64><<<BN / 256, 256, 0, stream>>>(XT1, SQ);
  knn_kernel<64><<<BN / 128, 256, 0, stream>>>(XT1, SQ, IDX);
  conv_fast<64, 64><<<BN, 256, 0, stream>>>(XT1, IDX, W2, g2, b2, m2, v2, XT2);
  // stage 3
  sq_kernel<64><<<BN / 256, 256, 0, stream>>>(XT2, SQ);
  knn_kernel<64><<<BN / 128, 256, 0, stream>>>(XT2, SQ, IDX);
  conv_fast<128, 64><<<BN, 256, 0, stream>>>(XT2, IDX, W3, g3, b3, m3, v3, XT3);
  // stage 4
  sq_kernel<128><<<BN / 256, 256, 0, stream>>>(XT3, SQ);
  knn_kernel<128><<<BN / 128, 256, 0, stream>>>(XT3, SQ, IDX);
  conv_fast<256, 128><<<BN, 256, 0, stream>>>(XT3, IDX, W4, g4, b4, m4, v4, XT4);
  // final
  final_kernel<<<BATCH * 128, 256, 0, stream>>>(XT1, XT2, XT3, XT4, W5, g5, b5, m5, v5, RED);
  reduce_kernel<<<BATCH, 256, 0, stream>>>(RED, out);
}

// Round 5
// 5502.257 us; speedup vs baseline: 1.9616x; 1.9616x over previous
//
#include <hip/hip_runtime.h>

#define NPTS 2048
#define KNN_K 20
#define BATCH 16

constexpr float EPSV   = 1e-5f;
constexpr float SLOPEV = 0.2f;

__device__ __forceinline__ float dot4(float4 a, float4 b, float acc) {
  acc = fmaf(a.x, b.x, acc);
  acc = fmaf(a.y, b.y, acc);
  acc = fmaf(a.z, b.z, acc);
  acc = fmaf(a.w, b.w, acc);
  return acc;
}

// ---------------- squared norms: one thread per (b,n) ----------------
template<int C>
__global__ void sq_kernel(const float* __restrict__ XT, float* __restrict__ SQ) {
  int i = blockIdx.x * 256 + threadIdx.x;          // i = b*NPTS + n
  const float* r = XT + (long)i * C;
  float s = 0.f;
  if constexpr (C % 4 == 0) {
    const float4* r4 = (const float4*)r;
    #pragma unroll
    for (int c = 0; c < C / 4; ++c) { float4 v = r4[c]; s = dot4(v, v, s); }
  } else {
    #pragma unroll
    for (int c = 0; c < C; ++c) s = fmaf(r[c], r[c], s);
  }
  SQ[i] = s;
}

// ---------------- KNN: 2 threads per row (halves of m-range) ----------------
// pd = 2*dot(xn,xm) - sq[n] - sq[m]; top-20 by value desc, ties -> lower index
template<int C>
__global__ __launch_bounds__(256, 1) void knn_kernel(const float* __restrict__ XT,
                                                     const float* __restrict__ SQ,
                                                     int* __restrict__ IDX) {
  __shared__ float ld[256][KNN_K];
  __shared__ int   li[256][KNN_K];
  int t    = threadIdx.x;
  int gr   = blockIdx.x * 128 + (t >> 1);          // global row = b*NPTS+n
  int b    = gr >> 11;
  int half = t & 1;

  float sqn = SQ[gr];
  const float* xb  = XT + ((long)b << 11) * C;
  const float* sqb = SQ + ((long)b << 11);

  float topd[KNN_K]; int topi[KNN_K];
  #pragma unroll
  for (int j = 0; j < KNN_K; ++j) { topd[j] = -3e38f; topi[j] = 0; }

  if constexpr (C % 4 == 0) {
    float4 xn4[C / 4];
    const float4* xr = (const float4*)(XT + (long)gr * C);
    #pragma unroll
    for (int c = 0; c < C / 4; ++c) xn4[c] = xr[c];

    int m0 = half << 10;
    for (int mm = 0; mm < 1024; ++mm) {
      int m = m0 + mm;
      const float4* xm4 = (const float4*)(xb + (long)m * C);
      float dot = 0.f;
      #pragma unroll
      for (int c = 0; c < C / 4; ++c) dot = dot4(xn4[c], xm4[c], dot);
      float pd = fmaf(2.f, dot, -sqn) - sqb[m];
      if (pd > topd[KNN_K - 1]) {
        float d = pd; int ii = m;
        #pragma unroll
        for (int j = 0; j < KNN_K; ++j) {
          bool sw = d > topd[j];
          float td = sw ? d : topd[j]; float dd = sw ? topd[j] : d;
          int   ti = sw ? ii : topi[j]; int  di = sw ? topi[j] : ii;
          topd[j] = td; d = dd; topi[j] = ti; ii = di;
        }
      }
    }
  } else {
    float xn[C];
    const float* xr = XT + (long)gr * C;
    #pragma unroll
    for (int c = 0; c < C; ++c) xn[c] = xr[c];

    int m0 = half << 10;
    for (int mm = 0; mm < 1024; ++mm) {
      int m = m0 + mm;
      const float* xm = xb + (long)m * C;
      float dot = 0.f;
      #pragma unroll
      for (int c = 0; c < C; ++c) dot = fmaf(xn[c], xm[c], dot);
      float pd = fmaf(2.f, dot, -sqn) - sqb[m];
      if (pd > topd[KNN_K - 1]) {
        float d = pd; int ii = m;
        #pragma unroll
        for (int j = 0; j < KNN_K; ++j) {
          bool sw = d > topd[j];
          float td = sw ? d : topd[j]; float dd = sw ? topd[j] : d;
          int   ti = sw ? ii : topi[j]; int  di = sw ? topi[j] : ii;
          topd[j] = td; d = dd; topi[j] = ti; ii = di;
        }
      }
    }
  }

  #pragma unroll
  for (int j = 0; j < KNN_K; ++j) { ld[t][j] = topd[j]; li[t][j] = topi[j]; }
  __syncthreads();

  if (t < 128) {
    int a = 2 * t, c2 = 2 * t + 1;
    int grow = blockIdx.x * 128 + t;
    int* dst = IDX + (long)grow * KNN_K;
    int ia = 0, ib = 0;
    for (int j = 0; j < KNN_K; ++j) {
      float da = ld[a][ia], db = ld[c2][ib];
      bool ta = (da >= db);                        // tie -> low half (lower m) first
      dst[j] = ta ? li[a][ia] : li[c2][ib];
      ia += ta ? 1 : 0; ib += ta ? 0 : 1;
    }
  }
}

// ---------------- edge conv stage 1 (C=3, scalar path) ----------------
template<int O, int C>
__global__ __launch_bounds__(256, 2) void conv_small(const float* __restrict__ XTin,
                                                     const int* __restrict__ IDX,
                                                     const float* __restrict__ W,
                                                     const float* __restrict__ gg,
                                                     const float* __restrict__ bbias,
                                                     const float* __restrict__ mmean,
                                                     const float* __restrict__ vvar,
                                                     float* __restrict__ XTout) {
  constexpr int G   = 256 / O;        // threads per o
  constexpr int KPG = KNN_K / G;      // k's per thread
  __shared__ float cols[KNN_K + 1][C];

  int bid = blockIdx.x;               // = b*NPTS + n
  int b = bid >> 11, n = bid & 2047;
  int t = threadIdx.x;
  long rowbase = ((long)b << 11);
  const int* idxp = IDX + (long)bid * KNN_K;

  for (int e = t; e < (KNN_K + 1) * C; e += 256) {
    int col = e / C, c = e - col * C;
    int j = (col == 0) ? n : idxp[col - 1];
    cols[col][c] = XTin[(rowbase + j) * C + c];
  }
  __syncthreads();

  int o = t / G, kg = t - o * G;
  const float* wrow = W + o * (2 * C);

  float acc[KPG];
  #pragma unroll
  for (int q = 0; q < KPG; ++q) acc[q] = 0.f;
  float s1 = 0.f, u2 = 0.f;

  #pragma unroll
  for (int c = 0; c < C; ++c) {
    float w1 = wrow[c];
    float w2 = wrow[C + c];
    float xn = cols[0][c];
    s1 = fmaf(w1, xn, s1);
    u2 = fmaf(w2, xn, u2);
    #pragma unroll
    for (int q = 0; q < KPG; ++q) {
      int k = kg * KPG + q;
      acc[q] = fmaf(w1, cols[1 + k][c], acc[q]);
    }
  }

  float sc = gg[o] / sqrtf(vvar[o] + EPSV);
  float sh = bbias[o] - mmean[o] * sc;
  float vmax = -3e38f;
  #pragma unroll
  for (int q = 0; q < KPG; ++q) {
    float z = acc[q] - s1 + u2;
    float y = fmaf(sc, z, sh);
    y = (y >= 0.f) ? y : SLOPEV * y;
    vmax = fmaxf(vmax, y);
  }
  #pragma unroll
  for (int off = 1; off < G; off <<= 1)
    vmax = fmaxf(vmax, __shfl_xor(vmax, off, 64));
  if (kg == 0) XTout[(rowbase + n) * O + o] = vmax;
}

// ---------------- A/BASE GEMM for stages 2-4 --------------------------------
// A[m][o]    = sum_c W[o][c]     * X[m][c]        (= W1 . x_m)
// BASE[m][o] = sum_c W[o][C+c]   * X[m][c] - A    (= (W2-W1) . x_m) -> XTout
// 16 points per block staged in LDS; thread (o = t%O, pg = t/O) owns NP=16*O/256... 
template<int O, int C>
__global__ __launch_bounds__(256, 2) void ad_kernel(const float* __restrict__ X,
                                                    const float* __restrict__ W,
                                                    float* __restrict__ A,
                                                    float* __restrict__ BASE) {
  static_assert(C % 4 == 0 && 256 % O == 0, "ad shape");
  constexpr int G  = 256 / O;   // point-groups
  constexpr int NP = 16 / G;    // points per thread
  constexpr int C4 = C / 4;
  __shared__ float xs[16][C];

  int blk = blockIdx.x;                 // 16-point tile
  long m0 = (long)blk * 16;
  int t = threadIdx.x;

  for (int e = t; e < 16 * C4; e += 256) {
    int pt = e / C4, c4 = e - pt * C4;
    *(float4*)&xs[pt][c4 * 4] = *(const float4*)(X + (m0 + pt) * C + c4 * 4);
  }
  __syncthreads();

  int o = t % O, pg = t / O;
  const float* wrow = W + o * (2 * C);

  float accA[NP], accD[NP];
  #pragma unroll
  for (int q = 0; q < NP; ++q) { accA[q] = 0.f; accD[q] = 0.f; }

  for (int c4 = 0; c4 < C4; ++c4) {
    float4 w1 = *(const float4*)(wrow + c4 * 4);
    float4 w2 = *(const float4*)(wrow + C + c4 * 4);
    #pragma unroll
    for (int q = 0; q < NP; ++q) {
      float4 xv = *(const float4*)&xs[pg * NP + q][c4 * 4];
      accA[q] = dot4(w1, xv, accA[q]);
      accD[q] = dot4(w2, xv, accD[q]);
    }
  }

  #pragma unroll
  for (int q = 0; q < NP; ++q) {
    long m = m0 + pg * NP + q;
    A[m * O + o]    = accA[q];
    BASE[m * O + o] = accD[q] - accA[q];
  }
}

// ---------------- gather-max: y[p][o] = max_k act(sc*(A[nb_k]+BASE[p])+sh) ---
// BASE lives in XTio (written by ad_kernel); result overwrites XTio in place.
template<int O>
__global__ __launch_bounds__(256, 4) void gather_kernel(const float* __restrict__ A,
                                                        const int* __restrict__ IDX,
                                                        const float* __restrict__ gg,
                                                        const float* __restrict__ bbias,
                                                        const float* __restrict__ mmean,
                                                        const float* __restrict__ vvar,
                                                        float* __restrict__ XTio) {
  constexpr int PPB = 256 / O;          // points per block
  int t = threadIdx.x;
  int o = t % O, pp = t / O;
  long p = (long)blockIdx.x * PPB + pp; // global point = b*NPTS + n
  int b = (int)(p >> 11);
  long rowbase = ((long)b << 11);
  const int* idxp = IDX + p * KNN_K;

  float base = XTio[p * O + o];
  float sc = gg[o] / sqrtf(vvar[o] + EPSV);
  float sh = bbias[o] - mmean[o] * sc;

  float vmax = -3e38f;
  #pragma unroll
  for (int k = 0; k < KNN_K; ++k) {
    int nb = idxp[k];
    float a = A[(rowbase + nb) * O + o];
    float y = fmaf(sc, a + base, sh);
    y = (y >= 0.f) ? y : SLOPEV * y;
    vmax = fmaxf(vmax, y);
  }
  XTio[p * O + o] = vmax;
}

// ---------------- final: y[b,o] = max_n act(s*W5·cat[b,:,n] + t) ----------------
__global__ __launch_bounds__(256, 2) void final_kernel(const float* __restrict__ X1,
                                                       const float* __restrict__ X2,
                                                       const float* __restrict__ X3,
                                                       const float* __restrict__ X4,
                                                       const float* __restrict__ W5,
                                                       const float* __restrict__ g5,
                                                       const float* __restrict__ b5,
                                                       const float* __restrict__ m5,
                                                       const float* __restrict__ v5,
                                                       float* __restrict__ RED) {
  __shared__ float tile[16][512];
  int bid = blockIdx.x;                 // b*128 + chunk
  int b = bid >> 7, chunk = bid & 127;
  int n0 = chunk * 16;
  int t = threadIdx.x;

  for (int e = t; e < 16 * 128; e += 256) {
    int nn = e >> 7, c4 = e & 127;
    int c = c4 * 4;
    long row = ((long)b << 11) + n0 + nn;
    float4 v;
    if      (c < 64)  v = *(const float4*)(X1 + row * 64  + c);
    else if (c < 128) v = *(const float4*)(X2 + row * 64  + (c - 64));
    else if (c < 256) v = *(const float4*)(X3 + row * 128 + (c - 128));
    else              v = *(const float4*)(X4 + row * 256 + (c - 256));
    *(float4*)&tile[nn][c] = v;
  }
  __syncthreads();

  int o = t;
  const float* wrow = W5 + o * 512;
  float acc[16];
  #pragma unroll
  for (int q = 0; q < 16; ++q) acc[q] = 0.f;
  for (int c4 = 0; c4 < 128; ++c4) {
    float4 w = *(const float4*)(wrow + c4 * 4);
    #pragma unroll
    for (int q = 0; q < 16; ++q) {
      float4 xv = *(const float4*)&tile[q][c4 * 4];
      acc[q] = dot4(w, xv, acc[q]);
    }
  }
  float sc = g5[o] / sqrtf(v5[o] + EPSV);
  float sh = b5[o] - m5[o] * sc;
  float vmax = -3e38f;
  #pragma unroll
  for (int q = 0; q < 16; ++q) {
    float y = fmaf(sc, acc[q], sh);
    y = (y >= 0.f) ? y : SLOPEV * y;
    vmax = fmaxf(vmax, y);
  }
  RED[((long)b * 256 + o) * 128 + chunk] = vmax;
}

__global__ void reduce_kernel(const float* __restrict__ RED, float* __restrict__ out) {
  int i = blockIdx.x * 256 + threadIdx.x;   // 4096 outputs
  const float* r = RED + (long)i * 128;
  float v = r[0];
  for (int j = 1; j < 128; ++j) v = fmaxf(v, r[j]);
  out[i] = v;
}

extern "C" void kernel_launch(void* const* d_in, const int* in_sizes, int n_in,
                              void* d_out, int out_size, void* d_ws, size_t ws_size,
                              hipStream_t stream) {
  (void)in_sizes; (void)n_in; (void)out_size; (void)ws_size;
  const float* pc = (const float*)d_in[0];                 // (16,2048,3) row-major = XT0
  const float* W1 = (const float*)d_in[1];
  const float* g1 = (const float*)d_in[2];
  const float* b1 = (const float*)d_in[3];
  const float* m1 = (const float*)d_in[4];
  const float* v1 = (const float*)d_in[5];
  const float* W2 = (const float*)d_in[6];
  const float* g2 = (const float*)d_in[7];
  const float* b2 = (const float*)d_in[8];
  const float* m2 = (const float*)d_in[9];
  const float* v2 = (const float*)d_in[10];
  const float* W3 = (const float*)d_in[11];
  const float* g3 = (const float*)d_in[12];
  const float* b3 = (const float*)d_in[13];
  const float* m3 = (const float*)d_in[14];
  const float* v3 = (const float*)d_in[15];
  const float* W4 = (const float*)d_in[16];
  const float* g4 = (const float*)d_in[17];
  const float* b4 = (const float*)d_in[18];
  const float* m4 = (const float*)d_in[19];
  const float* v4 = (const float*)d_in[20];
  const float* W5 = (const float*)d_in[21];
  const float* g5 = (const float*)d_in[22];
  const float* b5 = (const float*)d_in[23];
  const float* m5 = (const float*)d_in[24];
  const float* v5 = (const float*)d_in[25];
  float* out = (float*)d_out;

  // workspace carving (floats), all row-major [b][n][C]
  float* XT1 = (float*)d_ws;            // 16*2048*64   = 2097152
  float* XT2 = XT1 + 2097152;           // 16*2048*64   = 2097152
  float* XT3 = XT2 + 2097152;           // 16*2048*128  = 4194304
  float* XT4 = XT3 + 4194304;           // 16*2048*256  = 8388608
  float* SQ  = XT4 + 8388608;           // 16*2048      = 32768
  float* RED = SQ  + 32768;             // 16*256*128   = 524288
  int*   IDX = (int*)(RED + 524288);    // 16*2048*20   = 655360 ints
  float* AD  = (float*)(IDX + 655360);  // 16*2048*256  = 8388608 (A buffer, reused per stage)

  const int BN = BATCH * NPTS;          // 32768

  // stage 1 (C=3 from pc)
  sq_kernel<3><<<BN / 256, 256, 0, stream>>>(pc, SQ);
  knn_kernel<3><<<BN / 128, 256, 0, stream>>>(pc, SQ, IDX);
  conv_small<64, 3><<<BN, 256, 0, stream>>>(pc, IDX, W1, g1, b1, m1, v1, XT1);
  // stage 2
  sq_kernel<64><<<BN / 256, 256, 0, stream>>>(XT1, SQ);
  knn_kernel<64><<<BN / 128, 256, 0, stream>>>(XT1, SQ, IDX);
  ad_kernel<64, 64><<<BN / 16, 256, 0, stream>>>(XT1, W2, AD, XT2);
  gather_kernel<64><<<BN / 4, 256, 0, stream>>>(AD, IDX, g2, b2, m2, v2, XT2);
  // stage 3
  sq_kernel<64><<<BN / 256, 256, 0, stream>>>(XT2, SQ);
  knn_kernel<64><<<BN / 128, 256, 0, stream>>>(XT2, SQ, IDX);
  ad_kernel<128, 64><<<BN / 16, 256, 0, stream>>>(XT2, W3, AD, XT3);
  gather_kernel<128><<<BN / 2, 256, 0, stream>>>(AD, IDX, g3, b3, m3, v3, XT3);
  // stage 4
  sq_kernel<128><<<BN / 256, 256, 0, stream>>>(XT3, SQ);
  knn_kernel<128><<<BN / 128, 256, 0, stream>>>(XT3, SQ, IDX);
  ad_kernel<256, 128><<<BN / 16, 256, 0, stream>>>(XT3, W4, AD, XT4);
  gather_kernel<256><<<BN, 256, 0, stream>>>(AD, IDX, g4, b4, m4, v4, XT4);
  // final
  final_kernel<<<BATCH * 128, 256, 0, stream>>>(XT1, XT2, XT3, XT4, W5, g5, b5, m5, v5, RED);
  reduce_kernel<<<BATCH, 256, 0, stream>>>(RED, out);
}

// Round 6
// 2703.182 us; speedup vs baseline: 3.9929x; 2.0355x over previous
//
#include <hip/hip_runtime.h>

#define NPTS 2048
#define KNN_K 20
#define BATCH 16

constexpr float EPSV   = 1e-5f;
constexpr float SLOPEV = 0.2f;

__device__ __forceinline__ float dot4(float4 a, float4 b, float acc) {
  acc = fmaf(a.x, b.x, acc);
  acc = fmaf(a.y, b.y, acc);
  acc = fmaf(a.z, b.z, acc);
  acc = fmaf(a.w, b.w, acc);
  return acc;
}

// insert (val, idx) into sorted-desc 20-list, strict > keeps earlier (lower) idx on ties
#define INSERT20(VAL, IDXV)                                              \
  if ((VAL) > topd[KNN_K - 1]) {                                         \
    float d_ = (VAL); int i_ = (IDXV);                                   \
    _Pragma("unroll")                                                    \
    for (int j_ = 0; j_ < KNN_K; ++j_) {                                 \
      bool sw_ = d_ > topd[j_];                                          \
      float td_ = sw_ ? d_ : topd[j_]; float dd_ = sw_ ? topd[j_] : d_;  \
      int   ti_ = sw_ ? i_ : topi[j_]; int  di_ = sw_ ? topi[j_] : i_;   \
      topd[j_] = td_; d_ = dd_; topi[j_] = ti_; i_ = di_;                \
    }                                                                    \
  }

// ---------------- pad pc (C=3) to X0P (C=4, w=0) ----------------
__global__ void pad_kernel(const float* __restrict__ pc, float* __restrict__ X0P) {
  int i = blockIdx.x * 256 + threadIdx.x;      // point id
  float4 v;
  v.x = pc[i * 3 + 0]; v.y = pc[i * 3 + 1]; v.z = pc[i * 3 + 2]; v.w = 0.f;
  ((float4*)X0P)[i] = v;
}

// ---------------- squared norms: one thread per (b,n) ----------------
template<int C>
__global__ void sq_kernel(const float* __restrict__ XT, float* __restrict__ SQ) {
  int i = blockIdx.x * 256 + threadIdx.x;      // i = b*NPTS + n
  const float4* r4 = (const float4*)(XT + (long)i * C);
  float s = 0.f;
  #pragma unroll
  for (int c = 0; c < C / 4; ++c) { float4 v = r4[c]; s = dot4(v, v, s); }
  SQ[i] = s;
}

// ---------------- distance GEMM: D[bb][n][m] = 2*x_n.x_m - sq[n] - sq[m] -----
// chunk of 4 batches; 128x128 tile per block; thread = 8x8 outputs.
template<int C>
__global__ __launch_bounds__(256, 2) void dist_kernel(const float* __restrict__ X,   // chunk base [4][NPTS][C]
                                                      const float* __restrict__ SQc, // chunk base [4*NPTS]
                                                      float* __restrict__ D) {       // [4][NPTS][NPTS]
  constexpr int KC = (C % 8 == 0) ? 8 : C;     // 8, or 4 for C=4
  __shared__ float As[KC][132];
  __shared__ float Bs[KC][132];
  int lin = blockIdx.x;
  int bb = lin >> 8;                 // batch within chunk
  int tile = lin & 255;
  int tn = tile >> 4, tm = tile & 15;
  int t = threadIdx.x;
  int tx = t & 15, ty = t >> 4;      // tx -> m cols, ty -> n rows
  long base = (long)bb * NPTS;
  const float* Xb = X + base * C;
  int n0 = tn * 128, m0 = tm * 128;

  float acc[8][8];
  #pragma unroll
  for (int i = 0; i < 8; ++i)
    #pragma unroll
    for (int j = 0; j < 8; ++j) acc[i][j] = 0.f;

  for (int k0 = 0; k0 < C; k0 += KC) {
    // stage A rows (n-tile) and B rows (m-tile), transposed to [k][point]
    for (int e = t; e < 32 * KC; e += 256) {
      int row = e / (KC / 4), c4 = e % (KC / 4);
      float4 v = *(const float4*)(Xb + (long)(n0 + row) * C + k0 + c4 * 4);
      As[c4 * 4 + 0][row] = v.x; As[c4 * 4 + 1][row] = v.y;
      As[c4 * 4 + 2][row] = v.z; As[c4 * 4 + 3][row] = v.w;
    }
    for (int e = t; e < 32 * KC; e += 256) {
      int row = e / (KC / 4), c4 = e % (KC / 4);
      float4 v = *(const float4*)(Xb + (long)(m0 + row) * C + k0 + c4 * 4);
      Bs[c4 * 4 + 0][row] = v.x; Bs[c4 * 4 + 1][row] = v.y;
      Bs[c4 * 4 + 2][row] = v.z; Bs[c4 * 4 + 3][row] = v.w;
    }
    __syncthreads();
    #pragma unroll
    for (int k = 0; k < KC; ++k) {
      float4 a0 = *(const float4*)&As[k][ty * 8];
      float4 a1 = *(const float4*)&As[k][ty * 8 + 4];
      float4 b0 = *(const float4*)&Bs[k][tx * 8];
      float4 b1 = *(const float4*)&Bs[k][tx * 8 + 4];
      float av[8] = {a0.x, a0.y, a0.z, a0.w, a1.x, a1.y, a1.z, a1.w};
      float bv[8] = {b0.x, b0.y, b0.z, b0.w, b1.x, b1.y, b1.z, b1.w};
      #pragma unroll
      for (int i = 0; i < 8; ++i)
        #pragma unroll
        for (int j = 0; j < 8; ++j)
          acc[i][j] = fmaf(av[i], bv[j], acc[i][j]);
    }
    __syncthreads();
  }

  float sqn[8], sqm[8];
  #pragma unroll
  for (int i = 0; i < 8; ++i) sqn[i] = SQc[base + n0 + ty * 8 + i];
  #pragma unroll
  for (int j = 0; j < 8; ++j) sqm[j] = SQc[base + m0 + tx * 8 + j];

  #pragma unroll
  for (int i = 0; i < 8; ++i) {
    float* drow = D + (base + n0 + ty * 8 + i) * NPTS + m0 + tx * 8;
    float4 w0, w1;
    w0.x = fmaf(2.f, acc[i][0], -sqn[i]) - sqm[0];
    w0.y = fmaf(2.f, acc[i][1], -sqn[i]) - sqm[1];
    w0.z = fmaf(2.f, acc[i][2], -sqn[i]) - sqm[2];
    w0.w = fmaf(2.f, acc[i][3], -sqn[i]) - sqm[3];
    w1.x = fmaf(2.f, acc[i][4], -sqn[i]) - sqm[4];
    w1.y = fmaf(2.f, acc[i][5], -sqn[i]) - sqm[5];
    w1.z = fmaf(2.f, acc[i][6], -sqn[i]) - sqm[6];
    w1.w = fmaf(2.f, acc[i][7], -sqn[i]) - sqm[7];
    *(float4*)drow = w0;
    *(float4*)(drow + 4) = w1;
  }
}

// ---------------- top-20 select: 8 threads per row, 8-way merge --------------
__global__ __launch_bounds__(256, 2) void select_kernel(const float* __restrict__ D,
                                                        int* __restrict__ IDXc) {
  __shared__ float ld[256][KNN_K];
  __shared__ int   li[256][KNN_K];
  int t = threadIdx.x;
  int rloc = t >> 3, q = t & 7;
  long row = (long)blockIdx.x * 32 + rloc;      // within chunk [4*NPTS)
  const float4* dr = (const float4*)(D + row * NPTS + q * 256);

  float topd[KNN_K]; int topi[KNN_K];
  #pragma unroll
  for (int j = 0; j < KNN_K; ++j) { topd[j] = -3e38f; topi[j] = 0; }

  int mb = q * 256;
  for (int j4 = 0; j4 < 64; ++j4) {
    float4 v = dr[j4];
    int m = mb + j4 * 4;
    INSERT20(v.x, m + 0);
    INSERT20(v.y, m + 1);
    INSERT20(v.z, m + 2);
    INSERT20(v.w, m + 3);
  }

  #pragma unroll
  for (int j = 0; j < KNN_K; ++j) { ld[t][j] = topd[j]; li[t][j] = topi[j]; }
  __syncthreads();

  if (q == 0) {
    int* dst = IDXc + row * KNN_K;
    int ia[8];
    #pragma unroll
    for (int l = 0; l < 8; ++l) ia[l] = 0;
    for (int j = 0; j < KNN_K; ++j) {
      float best = ld[t][ia[0]]; int bl = 0;
      #pragma unroll
      for (int l = 1; l < 8; ++l) {
        float v = ld[t + l][ia[l]];
        if (v > best) { best = v; bl = l; }      // strict > : tie -> lowest q (lowest m)
      }
      dst[j] = li[t + bl][ia[bl]];
      #pragma unroll
      for (int l = 0; l < 8; ++l) ia[l] += (l == bl) ? 1 : 0;
    }
  }
}

// ---------------- edge conv stage 1 (C=3, scalar path) ----------------
template<int O, int C>
__global__ __launch_bounds__(256, 2) void conv_small(const float* __restrict__ XTin,
                                                     const int* __restrict__ IDX,
                                                     const float* __restrict__ W,
                                                     const float* __restrict__ gg,
                                                     const float* __restrict__ bbias,
                                                     const float* __restrict__ mmean,
                                                     const float* __restrict__ vvar,
                                                     float* __restrict__ XTout) {
  constexpr int G   = 256 / O;
  constexpr int KPG = KNN_K / G;
  __shared__ float cols[KNN_K + 1][C];

  int bid = blockIdx.x;               // = b*NPTS + n
  int b = bid >> 11, n = bid & 2047;
  int t = threadIdx.x;
  long rowbase = ((long)b << 11);
  const int* idxp = IDX + (long)bid * KNN_K;

  for (int e = t; e < (KNN_K + 1) * C; e += 256) {
    int col = e / C, c = e - col * C;
    int j = (col == 0) ? n : idxp[col - 1];
    cols[col][c] = XTin[(rowbase + j) * C + c];
  }
  __syncthreads();

  int o = t / G, kg = t - o * G;
  const float* wrow = W + o * (2 * C);

  float acc[KPG];
  #pragma unroll
  for (int q = 0; q < KPG; ++q) acc[q] = 0.f;
  float s1 = 0.f, u2 = 0.f;

  #pragma unroll
  for (int c = 0; c < C; ++c) {
    float w1 = wrow[c];
    float w2 = wrow[C + c];
    float xn = cols[0][c];
    s1 = fmaf(w1, xn, s1);
    u2 = fmaf(w2, xn, u2);
    #pragma unroll
    for (int q = 0; q < KPG; ++q) {
      int k = kg * KPG + q;
      acc[q] = fmaf(w1, cols[1 + k][c], acc[q]);
    }
  }

  float sc = gg[o] / sqrtf(vvar[o] + EPSV);
  float sh = bbias[o] - mmean[o] * sc;
  float vmax = -3e38f;
  #pragma unroll
  for (int q = 0; q < KPG; ++q) {
    float z = acc[q] - s1 + u2;
    float y = fmaf(sc, z, sh);
    y = (y >= 0.f) ? y : SLOPEV * y;
    vmax = fmaxf(vmax, y);
  }
  #pragma unroll
  for (int off = 1; off < G; off <<= 1)
    vmax = fmaxf(vmax, __shfl_xor(vmax, off, 64));
  if (kg == 0) XTout[(rowbase + n) * O + o] = vmax;
}

// ---------------- A/BASE GEMM for stages 2-4 --------------------------------
template<int O, int C>
__global__ __launch_bounds__(256, 2) void ad_kernel(const float* __restrict__ X,
                                                    const float* __restrict__ W,
                                                    float* __restrict__ A,
                                                    float* __restrict__ BASE) {
  static_assert(C % 4 == 0 && 256 % O == 0, "ad shape");
  constexpr int G  = 256 / O;
  constexpr int NP = 16 / G;
  constexpr int C4 = C / 4;
  __shared__ float xs[16][C];

  int blk = blockIdx.x;
  long m0 = (long)blk * 16;
  int t = threadIdx.x;

  for (int e = t; e < 16 * C4; e += 256) {
    int pt = e / C4, c4 = e - pt * C4;
    *(float4*)&xs[pt][c4 * 4] = *(const float4*)(X + (m0 + pt) * C + c4 * 4);
  }
  __syncthreads();

  int o = t % O, pg = t / O;
  const float* wrow = W + o * (2 * C);

  float accA[NP], accD[NP];
  #pragma unroll
  for (int q = 0; q < NP; ++q) { accA[q] = 0.f; accD[q] = 0.f; }

  for (int c4 = 0; c4 < C4; ++c4) {
    float4 w1 = *(const float4*)(wrow + c4 * 4);
    float4 w2 = *(const float4*)(wrow + C + c4 * 4);
    #pragma unroll
    for (int q = 0; q < NP; ++q) {
      float4 xv = *(const float4*)&xs[pg * NP + q][c4 * 4];
      accA[q] = dot4(w1, xv, accA[q]);
      accD[q] = dot4(w2, xv, accD[q]);
    }
  }

  #pragma unroll
  for (int q = 0; q < NP; ++q) {
    long m = m0 + pg * NP + q;
    A[m * O + o]    = accA[q];
    BASE[m * O + o] = accD[q] - accA[q];
  }
}

// ---------------- gather-max: y[p][o] = max_k act(sc*(A[nb_k]+BASE[p])+sh) ---
template<int O>
__global__ __launch_bounds__(256, 4) void gather_kernel(const float* __restrict__ A,
                                                        const int* __restrict__ IDX,
                                                        const float* __restrict__ gg,
                                                        const float* __restrict__ bbias,
                                                        const float* __restrict__ mmean,
                                                        const float* __restrict__ vvar,
                                                        float* __restrict__ XTio) {
  constexpr int PPB = 256 / O;
  int t = threadIdx.x;
  int o = t % O, pp = t / O;
  long p = (long)blockIdx.x * PPB + pp;
  int b = (int)(p >> 11);
  long rowbase = ((long)b << 11);
  const int* idxp = IDX + p * KNN_K;

  float base = XTio[p * O + o];
  float sc = gg[o] / sqrtf(vvar[o] + EPSV);
  float sh = bbias[o] - mmean[o] * sc;

  float vmax = -3e38f;
  #pragma unroll
  for (int k = 0; k < KNN_K; ++k) {
    int nb = idxp[k];
    float a = A[(rowbase + nb) * O + o];
    float y = fmaf(sc, a + base, sh);
    y = (y >= 0.f) ? y : SLOPEV * y;
    vmax = fmaxf(vmax, y);
  }
  XTio[p * O + o] = vmax;
}

// ---------------- final + reduce ----------------
__global__ __launch_bounds__(256, 2) void final_kernel(const float* __restrict__ X1,
                                                       const float* __restrict__ X2,
                                                       const float* __restrict__ X3,
                                                       const float* __restrict__ X4,
                                                       const float* __restrict__ W5,
                                                       const float* __restrict__ g5,
                                                       const float* __restrict__ b5,
                                                       const float* __restrict__ m5,
                                                       const float* __restrict__ v5,
                                                       float* __restrict__ RED) {
  __shared__ float tile[16][512];
  int bid = blockIdx.x;                 // b*128 + chunk
  int b = bid >> 7, chunk = bid & 127;
  int n0 = chunk * 16;
  int t = threadIdx.x;

  for (int e = t; e < 16 * 128; e += 256) {
    int nn = e >> 7, c4 = e & 127;
    int c = c4 * 4;
    long row = ((long)b << 11) + n0 + nn;
    float4 v;
    if      (c < 64)  v = *(const float4*)(X1 + row * 64  + c);
    else if (c < 128) v = *(const float4*)(X2 + row * 64  + (c - 64));
    else if (c < 256) v = *(const float4*)(X3 + row * 128 + (c - 128));
    else              v = *(const float4*)(X4 + row * 256 + (c - 256));
    *(float4*)&tile[nn][c] = v;
  }
  __syncthreads();

  int o = t;
  const float* wrow = W5 + o * 512;
  float acc[16];
  #pragma unroll
  for (int q = 0; q < 16; ++q) acc[q] = 0.f;
  for (int c4 = 0; c4 < 128; ++c4) {
    float4 w = *(const float4*)(wrow + c4 * 4);
    #pragma unroll
    for (int q = 0; q < 16; ++q) {
      float4 xv = *(const float4*)&tile[q][c4 * 4];
      acc[q] = dot4(w, xv, acc[q]);
    }
  }
  float sc = g5[o] / sqrtf(v5[o] + EPSV);
  float sh = b5[o] - m5[o] * sc;
  float vmax = -3e38f;
  #pragma unroll
  for (int q = 0; q < 16; ++q) {
    float y = fmaf(sc, acc[q], sh);
    y = (y >= 0.f) ? y : SLOPEV * y;
    vmax = fmaxf(vmax, y);
  }
  RED[((long)b * 256 + o) * 128 + chunk] = vmax;
}

__global__ void reduce_kernel(const float* __restrict__ RED, float* __restrict__ out) {
  int i = blockIdx.x * 256 + threadIdx.x;
  const float* r = RED + (long)i * 128;
  float v = r[0];
  for (int j = 1; j < 128; ++j) v = fmaxf(v, r[j]);
  out[i] = v;
}

extern "C" void kernel_launch(void* const* d_in, const int* in_sizes, int n_in,
                              void* d_out, int out_size, void* d_ws, size_t ws_size,
                              hipStream_t stream) {
  (void)in_sizes; (void)n_in; (void)out_size; (void)ws_size;
  const float* pc = (const float*)d_in[0];
  const float* W1 = (const float*)d_in[1];
  const float* g1 = (const float*)d_in[2];
  const float* b1 = (const float*)d_in[3];
  const float* m1 = (const float*)d_in[4];
  const float* v1 = (const float*)d_in[5];
  const float* W2 = (const float*)d_in[6];
  const float* g2 = (const float*)d_in[7];
  const float* b2 = (const float*)d_in[8];
  const float* m2 = (const float*)d_in[9];
  const float* v2 = (const float*)d_in[10];
  const float* W3 = (const float*)d_in[11];
  const float* g3 = (const float*)d_in[12];
  const float* b3 = (const float*)d_in[13];
  const float* m3 = (const float*)d_in[14];
  const float* v3 = (const float*)d_in[15];
  const float* W4 = (const float*)d_in[16];
  const float* g4 = (const float*)d_in[17];
  const float* b4 = (const float*)d_in[18];
  const float* m4 = (const float*)d_in[19];
  const float* v4 = (const float*)d_in[20];
  const float* W5 = (const float*)d_in[21];
  const float* g5 = (const float*)d_in[22];
  const float* b5 = (const float*)d_in[23];
  const float* m5 = (const float*)d_in[24];
  const float* v5 = (const float*)d_in[25];
  float* out = (float*)d_out;

  // workspace layout (floats). D (4 batches x 2048^2 = 16777216) overlays XT4+AD
  // (= 16777216 exactly), which are dead during every stage's knn phase.
  float* XT1 = (float*)d_ws;            // 2097152
  float* XT2 = XT1 + 2097152;           // 2097152
  float* XT3 = XT2 + 2097152;           // 4194304
  float* XT4 = XT3 + 4194304;           // 8388608
  float* AD  = XT4 + 8388608;           // 8388608
  float* D   = XT4;                     // overlay: 16777216
  float* SQ  = AD  + 8388608;           // 32768
  float* RED = SQ  + 32768;             // 524288
  int*   IDX = (int*)(RED + 524288);    // 655360 ints
  float* X0P = (float*)(IDX + 655360);  // 131072

  const int BN = BATCH * NPTS;          // 32768
  const long CHB = 4L * NPTS;           // rows per chunk (4 batches)

  // ---- stage 1 (C=3 -> padded C=4) ----
  pad_kernel<<<BN / 256, 256, 0, stream>>>(pc, X0P);
  sq_kernel<4><<<BN / 256, 256, 0, stream>>>(X0P, SQ);
  for (int ch = 0; ch < 4; ++ch) {
    dist_kernel<4><<<1024, 256, 0, stream>>>(X0P + ch * CHB * 4, SQ + ch * CHB, D);
    select_kernel<<<256, 256, 0, stream>>>(D, IDX + ch * CHB * KNN_K);
  }
  conv_small<64, 3><<<BN, 256, 0, stream>>>(pc, IDX, W1, g1, b1, m1, v1, XT1);

  // ---- stage 2 (C=64 -> O=64) ----
  sq_kernel<64><<<BN / 256, 256, 0, stream>>>(XT1, SQ);
  for (int ch = 0; ch < 4; ++ch) {
    dist_kernel<64><<<1024, 256, 0, stream>>>(XT1 + ch * CHB * 64, SQ + ch * CHB, D);
    select_kernel<<<256, 256, 0, stream>>>(D, IDX + ch * CHB * KNN_K);
  }
  ad_kernel<64, 64><<<BN / 16, 256, 0, stream>>>(XT1, W2, AD, XT2);
  gather_kernel<64><<<BN / 4, 256, 0, stream>>>(AD, IDX, g2, b2, m2, v2, XT2);

  // ---- stage 3 (C=64 -> O=128) ----
  sq_kernel<64><<<BN / 256, 256, 0, stream>>>(XT2, SQ);
  for (int ch = 0; ch < 4; ++ch) {
    dist_kernel<64><<<1024, 256, 0, stream>>>(XT2 + ch * CHB * 64, SQ + ch * CHB, D);
    select_kernel<<<256, 256, 0, stream>>>(D, IDX + ch * CHB * KNN_K);
  }
  ad_kernel<128, 64><<<BN / 16, 256, 0, stream>>>(XT2, W3, AD, XT3);
  gather_kernel<128><<<BN / 2, 256, 0, stream>>>(AD, IDX, g3, b3, m3, v3, XT3);

  // ---- stage 4 (C=128 -> O=256) ----
  sq_kernel<128><<<BN / 256, 256, 0, stream>>>(XT3, SQ);
  for (int ch = 0; ch < 4; ++ch) {
    dist_kernel<128><<<1024, 256, 0, stream>>>(XT3 + ch * CHB * 128, SQ + ch * CHB, D);
    select_kernel<<<256, 256, 0, stream>>>(D, IDX + ch * CHB * KNN_K);
  }
  ad_kernel<256, 128><<<BN / 16, 256, 0, stream>>>(XT3, W4, AD, XT4);
  gather_kernel<256><<<BN, 256, 0, stream>>>(AD, IDX, g4, b4, m4, v4, XT4);

  // ---- final ----
  final_kernel<<<BATCH * 128, 256, 0, stream>>>(XT1, XT2, XT3, XT4, W5, g5, b5, m5, v5, RED);
  reduce_kernel<<<BATCH, 256, 0, stream>>>(RED, out);
}